// Round 10
// baseline (178.373 us; speedup 1.0000x reference)
//
#include <hip/hip_runtime.h>
#include <hip/hip_bf16.h>
#include <math.h>

// ---- problem constants ----
#define B_ROWS 512
#define D_K    512
#define C_CLS  100000
#define C_PAD  100032                   // NCHUNK*64 (pad rows = fp8 zeros)

#define COS_M 0.8775825618903728f
#define SIN_M 0.479425538604203f
#define TH_C  (-0.8775825618903728f)    // cos(pi - m)
#define MM_C  0.2397127693021015f       // sin(pi - m) * m

#define LOG2E_S 92.33248261689366f      // 64 * log2(e)
#define M0      92.4f                   // fixed softmax bound: |cos|<=1 -> |L|<=92.33
#define LN2F    0.6931471805599453f

// ---- GEMM tile config ----
#define BN 64                           // classes per chunk
#define NCHUNK 1563                     // ceil(100000/64)
#define NSTRIP 256                      // col-strips; strip s covers chunks [s*1563/256,(s+1)*1563/256)

typedef __attribute__((ext_vector_type(4))) float f32x4;
typedef long long i64;

__device__ inline float fexp2(float x) {
#if __has_builtin(__builtin_amdgcn_exp2f)
    return __builtin_amdgcn_exp2f(x);
#else
    return exp2f(x);
#endif
}

// ---------------- kernel 0: row-normalize -> fp8 e4m3 (4 rows/block) ----------------
// in[r][0..511] fp32 -> normalized fp8 (OCP e4m3); rows >= nvalid get zeros.
__global__ __launch_bounds__(256) void rownorm8_kernel(const float* __restrict__ in,
                                                       uint2* __restrict__ out,
                                                       float* __restrict__ rnout,
                                                       int nvalid) {
    const int wid = threadIdx.x >> 6;
    const int lane = threadIdx.x & 63;
    const int r = blockIdx.x * 4 + wid;
    if (r >= nvalid) {
        out[(size_t)r * 64 + lane] = make_uint2(0u, 0u);
        return;
    }
    const float* row = in + (size_t)r * D_K + lane * 8;
    float4 a = *(const float4*)row;
    float4 b = *(const float4*)(row + 4);
    float ss = a.x * a.x + a.y * a.y + a.z * a.z + a.w * a.w
             + b.x * b.x + b.y * b.y + b.z * b.z + b.w * b.w;
    ss += __shfl_xor(ss, 1);  ss += __shfl_xor(ss, 2);  ss += __shfl_xor(ss, 4);
    ss += __shfl_xor(ss, 8);  ss += __shfl_xor(ss, 16); ss += __shfl_xor(ss, 32);
    const float rn = 1.0f / sqrtf(ss);
    int u0 = __builtin_amdgcn_cvt_pk_fp8_f32(a.x * rn, a.y * rn, 0, false);
    u0     = __builtin_amdgcn_cvt_pk_fp8_f32(a.z * rn, a.w * rn, u0, true);
    int u1 = __builtin_amdgcn_cvt_pk_fp8_f32(b.x * rn, b.y * rn, 0, false);
    u1     = __builtin_amdgcn_cvt_pk_fp8_f32(b.z * rn, b.w * rn, u1, true);
    out[(size_t)r * 64 + lane] = make_uint2((unsigned)u0, (unsigned)u1);
    if (rnout != nullptr && lane == 0) rnout[r] = rn;
}

// ---------------- kernel 1: barrier-free fp8 strip GEMM ----------------
// NO LDS, NO barriers. 256 thr / 4 waves; each wave owns 64 rows, A fp8 resident
// in regs (a8[4][16] = 128 VGPR). B frags (8B) loaded directly from wn8 (L3/L1-hot),
// depth-1 double-buffered (bf[2][8], static under unroll). Waves slip freely;
// compiler inserts vmcnt. Grid = 256 col-strips x 2 rowblocks = 512 = 2 blocks/CU.
__global__ __launch_bounds__(256, 2) void gemm_nolds_kernel(
        const unsigned char* __restrict__ xnb8,   // [512][512] fp8 normalized
        const unsigned char* __restrict__ wn8,    // [C_PAD][512] fp8 normalized (pad=0)
        float* __restrict__ partials) {           // [NSTRIP][512]
    const int t    = threadIdx.x;
    const int lane = t & 63;
    const int wid  = t >> 6;
    const int cl   = lane & 15;
    const int hi   = lane >> 4;

    const int j  = blockIdx.x;
    const int s  = j >> 1;               // col-strip
    const int rb = j & 1;                // rowblock (rows rb*256..+255)
    const int ch0 = (s * NCHUNK) >> 8;   // NSTRIP==256
    const int ch1 = ((s + 1) * NCHUNK) >> 8;
    const int nch = ch1 - ch0;
    const int cbase = ch0 * BN;

    // ---- A: 64 rows/wave, full K=512, fp8 resident (xnb8 is 256KB, L2/L3-hot) ----
    i64 a8[4][16];
#pragma unroll
    for (int m = 0; m < 4; ++m) {
        const unsigned char* ap =
            xnb8 + (size_t)(rb * 256 + wid * 64 + m * 16 + cl) * 512 + hi * 8;
#pragma unroll
        for (int ks = 0; ks < 8; ++ks) {
#pragma unroll
            for (int kk = 0; kk < 2; ++kk)
                a8[m][ks * 2 + kk] = *(const i64*)(ap + ks * 64 + kk * 32);
        }
    }

    // per-n B base pointers for this lane (class = cbase + n*16 + cl)
    const char* pB[4];
#pragma unroll
    for (int n = 0; n < 4; ++n)
        pB[n] = (const char*)wn8 + (size_t)(cbase + n * 16 + cl) * 512 + hi * 8;

    i64 bf[2][8];   // [parity][n (kk0) | 4+n (kk1)] -- all indices static under unroll
#define LOADB(gk, set)                                                        \
    {                                                                         \
        const int _ci = (gk) >> 3, _k = (gk) & 7;                             \
        const int _off = _ci * 32768 + _k * 64;                               \
        _Pragma("unroll")                                                     \
        for (int n = 0; n < 4; ++n) {                                         \
            bf[set][n]     = *(const i64*)(pB[n] + _off);                     \
            bf[set][4 + n] = *(const i64*)(pB[n] + _off + 32);                \
        }                                                                     \
    }

    float sums[16];
#pragma unroll
    for (int i = 0; i < 16; ++i) sums[i] = 0.f;

    LOADB(0, 0)

    for (int ci = 0; ci < nch; ++ci) {
        f32x4 acc[4][4];
#pragma unroll
        for (int m = 0; m < 4; ++m)
#pragma unroll
            for (int n = 0; n < 4; ++n) acc[m][n] = (f32x4){0.f, 0.f, 0.f, 0.f};

#pragma unroll
        for (int k = 0; k < 8; ++k) {
            // prefetch next kstep (next chunk's kstep0 when k==7)
            if (k < 7) {
                LOADB(ci * 8 + k + 1, (k + 1) & 1)
            } else if (ci + 1 < nch) {
                LOADB(ci * 8 + 8, 0)
            }
            // MFMA from bf[k&1]
#pragma unroll
            for (int m = 0; m < 4; ++m)
#pragma unroll
                for (int n = 0; n < 4; ++n)
                    acc[m][n] = __builtin_amdgcn_mfma_f32_16x16x32_fp8_fp8(
                        a8[m][k * 2], bf[k & 1][n], acc[m][n], 0, 0, 0);
#pragma unroll
            for (int m = 0; m < 4; ++m)
#pragma unroll
                for (int n = 0; n < 4; ++n)
                    acc[m][n] = __builtin_amdgcn_mfma_f32_16x16x32_fp8_fp8(
                        a8[m][k * 2 + 1], bf[k & 1][4 + n], acc[m][n], 0, 0, 0);
        }

        // fixed-M0 accumulation (rows pre-normalized; pad classes give 2^-92.4 ~ 0)
#pragma unroll
        for (int m = 0; m < 4; ++m)
#pragma unroll
            for (int jj = 0; jj < 4; ++jj)
#pragma unroll
                for (int n = 0; n < 4; ++n)
                    sums[m * 4 + jj] += fexp2(fmaf(acc[m][n][jj], LOG2E_S, -M0));
    }
#undef LOADB

    // ---- strip epilogue: reduce each tracked row across its 16 col-lanes ----
#pragma unroll
    for (int m = 0; m < 4; ++m)
#pragma unroll
        for (int jj = 0; jj < 4; ++jj) {
            float v = sums[m * 4 + jj];
            v += __shfl_xor(v, 1);
            v += __shfl_xor(v, 2);
            v += __shfl_xor(v, 4);
            v += __shfl_xor(v, 8);
            if (cl == 0) {
                const int r = rb * 256 + wid * 64 + m * 16 + hi * 4 + jj;
                partials[s * B_ROWS + r] = v;
            }
        }
}

// ---------------- kernel 2: target-class cosine (fp32 exact) ----------------
__global__ __launch_bounds__(256) void tdot_kernel(const float* __restrict__ x,
                                                   const float* __restrict__ w,
                                                   const int* __restrict__ tgt,
                                                   const float* __restrict__ xrn,
                                                   float* __restrict__ tdot) {
    const int wid = threadIdx.x >> 6;
    const int lane = threadIdx.x & 63;
    const int b = blockIdx.x * 4 + wid;
    const int tg = tgt[b];
    const float* xr = x + (size_t)b * D_K + lane * 8;
    const float* wr = w + (size_t)tg * D_K + lane * 8;
    float4 xa = *(const float4*)xr;
    float4 xb = *(const float4*)(xr + 4);
    float4 wa = *(const float4*)wr;
    float4 wb = *(const float4*)(wr + 4);
    float xw = xa.x * wa.x + xa.y * wa.y + xa.z * wa.z + xa.w * wa.w
             + xb.x * wb.x + xb.y * wb.y + xb.z * wb.z + xb.w * wb.w;
    float ww = wa.x * wa.x + wa.y * wa.y + wa.z * wa.z + wa.w * wa.w
             + wb.x * wb.x + wb.y * wb.y + wb.z * wb.z + wb.w * wb.w;
#pragma unroll
    for (int m = 1; m < 64; m <<= 1) {
        xw += __shfl_xor(xw, m);
        ww += __shfl_xor(ww, m);
    }
    if (lane == 0) tdot[b] = xw * xrn[b] / sqrtf(ww);
}

// ---------------- kernel 3: per-row loss (margin fixup) + mean ----------------
__global__ __launch_bounds__(512) void final_kernel(const float* __restrict__ partials,
                                                    const float* __restrict__ tdot,
                                                    float* __restrict__ out) {
    const int b = threadIdx.x;   // 512 threads = 8 waves
    float s2 = 0.f;
    for (int s = 0; s < NSTRIP; ++s) s2 += partials[s * B_ROWS + b];
    const float cst = tdot[b];
    float c2 = 1.0f - cst * cst;
    c2 = fminf(fmaxf(c2, 0.0f), 1.0f);
    const float sine = sqrtf(c2);
    float phi = cst * COS_M - sine * SIN_M;
    phi = (cst > TH_C) ? phi : (cst - MM_C);
    const float Lt = cst * LOG2E_S;
    const float Lp = phi * LOG2E_S;
    // swap plain-target term for margin term in the denominator
    s2 = s2 - fexp2(Lt - M0) + fexp2(Lp - M0);
    float loss = LN2F * (M0 + log2f(s2) - Lp);
    loss += __shfl_xor(loss, 1);  loss += __shfl_xor(loss, 2);
    loss += __shfl_xor(loss, 4);  loss += __shfl_xor(loss, 8);
    loss += __shfl_xor(loss, 16); loss += __shfl_xor(loss, 32);
    __shared__ float sW[8];
    if ((b & 63) == 0) sW[b >> 6] = loss;
    __syncthreads();
    if (b == 0) {
        float tot = 0.f;
#pragma unroll
        for (int wv = 0; wv < 8; ++wv) tot += sW[wv];
        out[0] = tot * (1.0f / (float)B_ROWS);
    }
}

extern "C" void kernel_launch(void* const* d_in, const int* in_sizes, int n_in,
                              void* d_out, int out_size, void* d_ws, size_t ws_size,
                              hipStream_t stream) {
    const float* x = (const float*)d_in[0];
    const float* w = (const float*)d_in[1];
    const int* tgt = (const int*)d_in[2];
    float* out = (float*)d_out;

    char* ws = (char*)d_ws;
    size_t off = 0;
    unsigned char* xnb8 = (unsigned char*)(ws + off);
    off += (size_t)B_ROWS * D_K;                       // 256 KB
    off = (off + 255) & ~(size_t)255;
    unsigned char* wn8 = (unsigned char*)(ws + off);
    off += (size_t)C_PAD * D_K;                        // 51.2 MB
    off = (off + 255) & ~(size_t)255;
    float* xrn = (float*)(ws + off);
    off += B_ROWS * 4;
    off = (off + 255) & ~(size_t)255;
    float* partials = (float*)(ws + off);
    off += (size_t)NSTRIP * B_ROWS * 4;                // 512 KB
    off = (off + 255) & ~(size_t)255;
    float* tdot = (float*)(ws + off);
    off += B_ROWS * 4;

    rownorm8_kernel<<<B_ROWS / 4, 256, 0, stream>>>(x, (uint2*)xnb8, xrn, B_ROWS);
    rownorm8_kernel<<<C_PAD / 4, 256, 0, stream>>>(w, (uint2*)wn8, nullptr, C_CLS);
    tdot_kernel<<<B_ROWS / 4, 256, 0, stream>>>(x, w, tgt, xrn, tdot);
    gemm_nolds_kernel<<<NSTRIP * 2, 256, 0, stream>>>(xnb8, wn8, partials);
    final_kernel<<<1, 512, 0, stream>>>(partials, tdot, out);
}

// Round 13
// 99.484 us; speedup vs baseline: 1.7930x; 1.7930x over previous
//
#include <hip/hip_runtime.h>
#include <hip/hip_bf16.h>
#include <math.h>

// ---- problem constants ----
#define B_ROWS 512
#define D_K    512
#define C_CLS  100000
#define C_PAD  100032                   // NCHUNK*64 (pad rows = fp8 zeros)

#define COS_M 0.8775825618903728f
#define SIN_M 0.479425538604203f
#define TH_C  (-0.8775825618903728f)    // cos(pi - m)
#define MM_C  0.2397127693021015f       // sin(pi - m) * m

#define LOG2E_S 92.33248261689366f      // 64 * log2(e)
#define M0      92.4f                   // fixed softmax bound: |cos|<=1 -> |L|<=92.33
#define LN2F    0.6931471805599453f

#define BN 64                           // classes per chunk
#define NCHUNK 1563                     // ceil(100000/64)
#define NSTRIP 256                      // col-strips

typedef __attribute__((ext_vector_type(4))) float f32x4;
typedef __attribute__((ext_vector_type(2))) long long i64x2;
typedef long long i64;

__device__ inline float fexp2(float x) {
#if __has_builtin(__builtin_amdgcn_exp2f)
    return __builtin_amdgcn_exp2f(x);
#else
    return exp2f(x);
#endif
}
__device__ inline void gload16(const void* g, void* lds) {
    __builtin_amdgcn_global_load_lds(
        (const __attribute__((address_space(1))) unsigned int*)g,
        (__attribute__((address_space(3))) unsigned int*)lds, 16, 0, 0);
}
#define VMCNT0() asm volatile("s_waitcnt vmcnt(0)" ::: "memory")
#define RAWBAR() __builtin_amdgcn_s_barrier()

// ---------------- kernel 0: row-normalize -> fp8 e4m3, kk-INTERLEAVED layout ------
// Permuted per-row byte order: pos = ks*64 + hi*16 + kk*8 + inner for original
// k-byte = ks*64 + kk*32 + hi*8 + inner.  So a 16B read at row*512+ks*64+hi*16
// yields the (kk0,kk1) MFMA fragment pair for lane-group hi, contiguous.
__global__ __launch_bounds__(256) void rownorm8p_kernel(const float* __restrict__ in,
                                                        uint2* __restrict__ out,
                                                        float* __restrict__ rnout,
                                                        int nvalid) {
    const int wid = threadIdx.x >> 6;
    const int lane = threadIdx.x & 63;
    const int r = blockIdx.x * 4 + wid;
    // permuted granule index for this lane's 8 source bytes (granule l of row)
    const int newg = ((lane >> 3) << 3) + ((lane & 3) << 1) + ((lane >> 2) & 1);
    if (r >= nvalid) {
        out[(size_t)r * 64 + newg] = make_uint2(0u, 0u);
        return;
    }
    const float* row = in + (size_t)r * D_K + lane * 8;
    float4 a = *(const float4*)row;
    float4 b = *(const float4*)(row + 4);
    float ss = a.x * a.x + a.y * a.y + a.z * a.z + a.w * a.w
             + b.x * b.x + b.y * b.y + b.z * b.z + b.w * b.w;
    ss += __shfl_xor(ss, 1);  ss += __shfl_xor(ss, 2);  ss += __shfl_xor(ss, 4);
    ss += __shfl_xor(ss, 8);  ss += __shfl_xor(ss, 16); ss += __shfl_xor(ss, 32);
    const float rn = 1.0f / sqrtf(ss);
    int u0 = __builtin_amdgcn_cvt_pk_fp8_f32(a.x * rn, a.y * rn, 0, false);
    u0     = __builtin_amdgcn_cvt_pk_fp8_f32(a.z * rn, a.w * rn, u0, true);
    int u1 = __builtin_amdgcn_cvt_pk_fp8_f32(b.x * rn, b.y * rn, 0, false);
    u1     = __builtin_amdgcn_cvt_pk_fp8_f32(b.z * rn, b.w * rn, u1, true);
    out[(size_t)r * 64 + newg] = make_uint2((unsigned)u0, (unsigned)u1);
    if (rnout != nullptr && lane == 0) rnout[r] = rn;
}

// ---------------- kernel 1: fp8 strip GEMM, chunk-level LDS double-buffer --------
// 256 thr / 4 waves; wave owns 64 rows; A fp8 pinned in regs (a8[4][16], 128 VGPR).
// Per chunk (64 classes x K=512 = 32 KB): stage next chunk via 8 global_load_lds
// (16B, pre-swizzled source), ONE vmcnt(0)+s_barrier per chunk. Within the chunk:
// 8 ksteps x {4 ds_read_b128 + 32 MFMA}, no barriers -> compiler pipelines.
// Bank swizzle: LDS granule16 = hi ^ ((row>>1)&3)  (worst 2-way, free).
__global__ __launch_bounds__(256, 2) void gemm_lds_kernel(
        const unsigned char* __restrict__ xnb8p,  // [512][512] fp8 norm, interleaved
        const unsigned char* __restrict__ wn8p,   // [C_PAD][512] fp8 norm, interleaved
        float* __restrict__ partials) {           // [NSTRIP][512]
    const int t    = threadIdx.x;
    const int lane = t & 63;
    const int wid  = t >> 6;
    const int cl   = lane & 15;
    const int hi   = lane >> 4;
    const int swz  = (cl >> 1) & 3;

    const int j  = blockIdx.x;
    const int s  = j >> 1;               // col-strip
    const int rb = j & 1;                // rowblock (rows rb*256..+255)
    const int ch0 = (s * NCHUNK) >> 8;   // NSTRIP==256
    const int ch1 = ((s + 1) * NCHUNK) >> 8;
    const int nch = ch1 - ch0;
    const int cbase = ch0 * BN;

    __shared__ char smem[2 * 32768];

    // staging identity: per slice k, thread t covers row wid*16+(lane>>2),
    // LDS granule lane&3; source granule pre-swizzled (involution).
    const int srow = wid * 16 + (lane >> 2);
    const int sgl  = (lane & 3) ^ ((lane >> 3) & 3);

#define STAGE_CHUNK(ci_, buf_)                                                   \
    {                                                                            \
        const unsigned char* _b =                                                \
            wn8p + (size_t)(cbase + (ci_) * 64 + srow) * 512 + (sgl << 4);       \
        char* _d = smem + (buf_) * 32768 + wid * 1024;                           \
        _Pragma("unroll")                                                        \
        for (int _k = 0; _k < 8; ++_k)                                           \
            gload16(_b + _k * 64, _d + _k * 4096);                               \
    }

    // ---- prologue: stage chunk 0; A -> registers (pinned) ----
    STAGE_CHUNK(0, 0)

    i64 a8[4][16];
#pragma unroll
    for (int m = 0; m < 4; ++m) {
        const unsigned char* ap =
            xnb8p + (size_t)(rb * 256 + wid * 64 + m * 16 + cl) * 512 + hi * 16;
#pragma unroll
        for (int k = 0; k < 8; ++k) {
            i64x2 q = *(const i64x2*)(ap + k * 64);
            a8[m][k * 2]     = q[0];
            a8[m][k * 2 + 1] = q[1];
        }
    }
    // pin A in VGPRs (defeat rematerialization of the global loads into the loop)
#pragma unroll
    for (int m = 0; m < 4; ++m)
#pragma unroll
        for (int i = 0; i < 16; ++i)
            asm volatile("" : "+v"(a8[m][i]));

    VMCNT0();
    __syncthreads();

    float sums[16];
#pragma unroll
    for (int i = 0; i < 16; ++i) sums[i] = 0.f;

    for (int ci = 0; ci < nch; ++ci) {
        if (ci + 1 < nch) { STAGE_CHUNK(ci + 1, (ci + 1) & 1) }
        __builtin_amdgcn_sched_barrier(0);   // keep stage issue ahead of compute

        f32x4 acc[4][4];
#pragma unroll
        for (int m = 0; m < 4; ++m)
#pragma unroll
            for (int n = 0; n < 4; ++n) acc[m][n] = (f32x4){0.f, 0.f, 0.f, 0.f};

        const char* sB = smem + (ci & 1) * 32768;
#pragma unroll
        for (int k = 0; k < 8; ++k) {
            i64x2 b[4];
#pragma unroll
            for (int n = 0; n < 4; ++n)
                b[n] = *(const i64x2*)(sB + k * 4096 + (n * 16 + cl) * 64 +
                                       ((hi ^ swz) << 4));
#pragma unroll
            for (int m = 0; m < 4; ++m)
#pragma unroll
                for (int n = 0; n < 4; ++n)
                    acc[m][n] = __builtin_amdgcn_mfma_f32_16x16x32_fp8_fp8(
                        a8[m][k * 2], b[n][0], acc[m][n], 0, 0, 0);
#pragma unroll
            for (int m = 0; m < 4; ++m)
#pragma unroll
                for (int n = 0; n < 4; ++n)
                    acc[m][n] = __builtin_amdgcn_mfma_f32_16x16x32_fp8_fp8(
                        a8[m][k * 2 + 1], b[n][1], acc[m][n], 0, 0, 0);
        }

        // fixed-M0 accumulation (pad classes: acc=0 -> 2^-92.4 ~ 0)
#pragma unroll
        for (int m = 0; m < 4; ++m)
#pragma unroll
            for (int jj = 0; jj < 4; ++jj)
#pragma unroll
                for (int n = 0; n < 4; ++n)
                    sums[m * 4 + jj] += fexp2(fmaf(acc[m][n][jj], LOG2E_S, -M0));

        VMCNT0();    // next chunk's 8 stage loads (issued ~2400 cy ago) landed
        RAWBAR();    // all waves done reading buf[ci&1]; buf[(ci+1)&1] ready
    }
#undef STAGE_CHUNK

    // ---- strip epilogue: reduce each tracked row across its 16 col-lanes ----
#pragma unroll
    for (int m = 0; m < 4; ++m)
#pragma unroll
        for (int jj = 0; jj < 4; ++jj) {
            float v = sums[m * 4 + jj];
            v += __shfl_xor(v, 1);
            v += __shfl_xor(v, 2);
            v += __shfl_xor(v, 4);
            v += __shfl_xor(v, 8);
            if (cl == 0) {
                const int r = rb * 256 + wid * 64 + m * 16 + hi * 4 + jj;
                partials[s * B_ROWS + r] = v;
            }
        }
}

// ---------------- kernel 2: target-class cosine (fp32 exact) ----------------
__global__ __launch_bounds__(256) void tdot_kernel(const float* __restrict__ x,
                                                   const float* __restrict__ w,
                                                   const int* __restrict__ tgt,
                                                   const float* __restrict__ xrn,
                                                   float* __restrict__ tdot) {
    const int wid = threadIdx.x >> 6;
    const int lane = threadIdx.x & 63;
    const int b = blockIdx.x * 4 + wid;
    const int tg = tgt[b];
    const float* xr = x + (size_t)b * D_K + lane * 8;
    const float* wr = w + (size_t)tg * D_K + lane * 8;
    float4 xa = *(const float4*)xr;
    float4 xb = *(const float4*)(xr + 4);
    float4 wa = *(const float4*)wr;
    float4 wb = *(const float4*)(wr + 4);
    float xw = xa.x * wa.x + xa.y * wa.y + xa.z * wa.z + xa.w * wa.w
             + xb.x * wb.x + xb.y * wb.y + xb.z * wb.z + xb.w * wb.w;
    float ww = wa.x * wa.x + wa.y * wa.y + wa.z * wa.z + wa.w * wa.w
             + wb.x * wb.x + wb.y * wb.y + wb.z * wb.z + wb.w * wb.w;
#pragma unroll
    for (int m = 1; m < 64; m <<= 1) {
        xw += __shfl_xor(xw, m);
        ww += __shfl_xor(ww, m);
    }
    if (lane == 0) tdot[b] = xw * xrn[b] / sqrtf(ww);
}

// ---------------- kernel 3: per-row loss (margin fixup) + mean ----------------
__global__ __launch_bounds__(512) void final_kernel(const float* __restrict__ partials,
                                                    const float* __restrict__ tdot,
                                                    float* __restrict__ out) {
    const int b = threadIdx.x;   // 512 threads = 8 waves
    float s2 = 0.f;
    for (int s = 0; s < NSTRIP; ++s) s2 += partials[s * B_ROWS + b];
    const float cst = tdot[b];
    float c2 = 1.0f - cst * cst;
    c2 = fminf(fmaxf(c2, 0.0f), 1.0f);
    const float sine = sqrtf(c2);
    float phi = cst * COS_M - sine * SIN_M;
    phi = (cst > TH_C) ? phi : (cst - MM_C);
    const float Lt = cst * LOG2E_S;
    const float Lp = phi * LOG2E_S;
    // swap plain-target term for margin term in the denominator
    s2 = s2 - fexp2(Lt - M0) + fexp2(Lp - M0);
    float loss = LN2F * (M0 + log2f(s2) - Lp);
    loss += __shfl_xor(loss, 1);  loss += __shfl_xor(loss, 2);
    loss += __shfl_xor(loss, 4);  loss += __shfl_xor(loss, 8);
    loss += __shfl_xor(loss, 16); loss += __shfl_xor(loss, 32);
    __shared__ float sW[8];
    if ((b & 63) == 0) sW[b >> 6] = loss;
    __syncthreads();
    if (b == 0) {
        float tot = 0.f;
#pragma unroll
        for (int wv = 0; wv < 8; ++wv) tot += sW[wv];
        out[0] = tot * (1.0f / (float)B_ROWS);
    }
}

extern "C" void kernel_launch(void* const* d_in, const int* in_sizes, int n_in,
                              void* d_out, int out_size, void* d_ws, size_t ws_size,
                              hipStream_t stream) {
    const float* x = (const float*)d_in[0];
    const float* w = (const float*)d_in[1];
    const int* tgt = (const int*)d_in[2];
    float* out = (float*)d_out;

    char* ws = (char*)d_ws;
    size_t off = 0;
    unsigned char* xnb8 = (unsigned char*)(ws + off);
    off += (size_t)B_ROWS * D_K;                       // 256 KB
    off = (off + 255) & ~(size_t)255;
    unsigned char* wn8 = (unsigned char*)(ws + off);
    off += (size_t)C_PAD * D_K;                        // 51.2 MB
    off = (off + 255) & ~(size_t)255;
    float* xrn = (float*)(ws + off);
    off += B_ROWS * 4;
    off = (off + 255) & ~(size_t)255;
    float* partials = (float*)(ws + off);
    off += (size_t)NSTRIP * B_ROWS * 4;                // 512 KB
    off = (off + 255) & ~(size_t)255;
    float* tdot = (float*)(ws + off);
    off += B_ROWS * 4;

    rownorm8p_kernel<<<B_ROWS / 4, 256, 0, stream>>>(x, (uint2*)xnb8, xrn, B_ROWS);
    rownorm8p_kernel<<<C_PAD / 4, 256, 0, stream>>>(w, (uint2*)wn8, nullptr, C_CLS);
    tdot_kernel<<<B_ROWS / 4, 256, 0, stream>>>(x, w, tgt, xrn, tdot);
    gemm_lds_kernel<<<NSTRIP * 2, 256, 0, stream>>>(xnb8, wn8, partials);
    final_kernel<<<1, 512, 0, stream>>>(partials, tdot, out);
}